// Round 6
// baseline (202.068 us; speedup 1.0000x reference)
//
#include <hip/hip_runtime.h>

#define BTOT 32768

using f32x4 = __attribute__((ext_vector_type(4))) float;
using half8 = __attribute__((ext_vector_type(8))) _Float16;

typedef const __attribute__((address_space(1))) unsigned int* gptr_t;
typedef __attribute__((address_space(3))) unsigned int* lptr_t;

__device__ __forceinline__ void gl2lds16(void* lds, const void* g) {
    __builtin_amdgcn_global_load_lds((gptr_t)g, (lptr_t)lds, 16, 0, 0);
}

__device__ __forceinline__ float sigm(float x) {
    return __builtin_amdgcn_rcpf(1.0f + __expf(-x));
}
__device__ __forceinline__ float tanh_(float x) {
    x = fminf(fmaxf(x, -15.0f), 15.0f);
    float e = __expf(2.0f * x);
    return (e - 1.0f) * __builtin_amdgcn_rcpf(e + 1.0f);
}

// ---------------------------------------------------------------------------
// Swizzled layouts: 128B rows of 8 x 16B granules, granule index XOR (row&7).
// LDS image == global image.
//   W1sw: [2 nb][2 kt][128][64]          Wsw: [4 tile][8 kt][192][64]
//   Xsw/H1sw: [8 kt][mb][rows][64]  (mb128 x 128 rows == mb256 x 256 rows)
// ---------------------------------------------------------------------------
__global__ __launch_bounds__(256) void pack_kernel(
    const float* __restrict__ W1,
    const float* __restrict__ Wih0, const float* __restrict__ bih0, const float* __restrict__ bhh0,
    const float* __restrict__ Wih1, const float* __restrict__ bih1, const float* __restrict__ bhh1,
    _Float16* __restrict__ W1sw,
    _Float16* __restrict__ W0sw, float* __restrict__ bp0,
    _Float16* __restrict__ W1sw_, float* __restrict__ bp1)
{
    int tid = blockIdx.x * 256 + threadIdx.x;
    if (tid < 256 * 64) {
        int n = tid >> 6, k = tid & 63;
        float v = (k < 63) ? 32.0f * W1[n * 63 + k] : 0.0f;
        _Float16 h = (_Float16)v;
        _Float16 l = (_Float16)(v - (float)h);
        int nb = n >> 7, r = n & 127, kt = k >> 5, kk = k & 31;
        size_t bb = (size_t)nb * 16384 + kt * 8192 + r * 64 + (kk & 7);
        W1sw[bb + ((((kk >> 3)) ^ (r & 7)) << 3)] = h;
        W1sw[bb + (((4 + (kk >> 3)) ^ (r & 7)) << 3)] = l;
    }
    int t2 = tid - 256 * 64;
    if (t2 >= 0 && t2 < 2 * 768 * 256) {
        int which = t2 / 196608;
        int rem   = t2 % 196608;
        int rlin = rem >> 8, k = rem & 255;
        int tile = rlin / 192;
        int rr = rlin - tile * 192;
        int g = rr >> 6, jj = rr & 63;
        int orig = ((g == 0) ? 0 : (g == 1) ? 512 : 768) + tile * 64 + jj;
        const float* W = which ? Wih1 : Wih0;
        float v = 32.0f * W[orig * 256 + k];
        _Float16 h = (_Float16)v;
        _Float16 l = (_Float16)(v - (float)h);
        int kt = k >> 5, kk = k & 31;
        _Float16* Wd = which ? W1sw_ : W0sw;
        size_t bb = (size_t)(tile * 8 + kt) * 12288 + rr * 64 + (kk & 7);
        Wd[bb + ((((kk >> 3)) ^ (rr & 7)) << 3)] = h;
        Wd[bb + (((4 + (kk >> 3)) ^ (rr & 7)) << 3)] = l;
        if (k == 0) {
            float bb2 = which ? (bih1[orig] + bhh1[orig]) : (bih0[orig] + bhh0[orig]);
            (which ? bp1 : bp0)[rlin] = bb2;
        }
    }
}

// ---------------------------------------------------------------------------
// GEMM1 with fused feature-prep. BM=128, BN=128 (grid.y=2), K=64.
// Output scattered to LDS then stored coalesced (half8).
// ---------------------------------------------------------------------------
__global__ __launch_bounds__(256) void gemm1_kernel(
    const float* __restrict__ aM, const float* __restrict__ RMB,
    const _Float16* __restrict__ W1sw, const float* __restrict__ b1,
    _Float16* __restrict__ Xsw, int nMB)
{
    __shared__ _Float16 sm[32768];   // A:[2kt][128][64]=16384, B same
    const int t = threadIdx.x;
    const int mb = blockIdx.x, nb = blockIdx.y;
    const int m0 = mb * 128;
    {
        int o = t * 8;
#pragma unroll
        for (int it = 0; it < 8; it++)
            gl2lds16(&sm[16384 + o + it * 2048], &W1sw[(size_t)nb * 16384 + o + it * 2048]);
    }
    if (t < 128) {
        int i = m0 + t;
        const float* ap = aM + (size_t)i * 18;
        const float* rp = RMB + (size_t)i * 54;
        float a[18], R[54];
#pragma unroll
        for (int q = 0; q < 9; q++)  { float2 v = *(const float2*)&ap[q * 2]; a[q*2] = v.x; a[q*2+1] = v.y; }
#pragma unroll
        for (int q = 0; q < 27; q++) { float2 v = *(const float2*)&rp[q * 2]; R[q*2] = v.x; R[q*2+1] = v.y; }
        const float* R6 = R + 45;
        float d[64];
        d[0] = -10.0f * R6[3]; d[1] = -10.0f * R6[4]; d[2] = -10.0f * R6[5];
#pragma unroll
        for (int n = 0; n < 5; n++) {
            float v0 = a[n*3+0] - a[15], v1 = a[n*3+1] - a[16], v2 = a[n*3+2] - a[17];
#pragma unroll
            for (int k = 0; k < 3; k++)
                d[3 + n*3 + k] = v0 * R6[k] + v1 * R6[3 + k] + v2 * R6[6 + k];
        }
#pragma unroll
        for (int n = 0; n < 5; n++)
#pragma unroll
            for (int ii = 0; ii < 3; ii++)
#pragma unroll
                for (int k = 0; k < 3; k++)
                    d[18 + n*9 + ii*3 + k] =
                        R6[ii] * R[n*9 + k] + R6[3 + ii] * R[n*9 + 3 + k] + R6[6 + ii] * R[n*9 + 6 + k];
        d[63] = 0.0f;
        int sx = t & 7;
#pragma unroll
        for (int kt = 0; kt < 2; kt++)
#pragma unroll
            for (int kg = 0; kg < 4; kg++) {
                _Float16 hh[8], ll[8];
#pragma unroll
                for (int e = 0; e < 8; e++) {
                    int di = kt * 32 + kg * 8 + e;
                    float v = (di < 63) ? 16.0f * d[di] : 0.0f;
                    _Float16 h = (_Float16)v;
                    hh[e] = h; ll[e] = (_Float16)(v - (float)h);
                }
                int base = kt * 8192 + t * 64;
                *(half8*)&sm[base + ((kg ^ sx) << 3)]       = *(half8*)hh;
                *(half8*)&sm[base + (((kg + 4) ^ sx) << 3)] = *(half8*)ll;
            }
    }
    asm volatile("s_waitcnt vmcnt(0)" ::: "memory");
    __syncthreads();
    const int lane = t & 63, wid = t >> 6;
    const int wr = wid >> 1, wc = wid & 1;
    const int r16 = lane & 15, g4 = lane >> 4;
    const int sx = r16 & 7;
    const int aghi = (g4 ^ sx) << 3;
    const int aglo = ((g4 + 4) ^ sx) << 3;
    f32x4 acc[4][4] = {};
#pragma unroll
    for (int kt = 0; kt < 2; kt++) {
        half8 ah[4], al[4];
#pragma unroll
        for (int i = 0; i < 4; i++) {
            int ra = kt * 8192 + (wr * 64 + i * 16 + r16) * 64;
            ah[i] = *(const half8*)&sm[ra + aghi];
            al[i] = *(const half8*)&sm[ra + aglo];
        }
#pragma unroll
        for (int j = 0; j < 4; j++) {
            int rb = 16384 + kt * 8192 + (wc * 64 + j * 16 + r16) * 64;
            half8 bh = *(const half8*)&sm[rb + aghi];
            half8 bl = *(const half8*)&sm[rb + aglo];
#pragma unroll
            for (int i = 0; i < 4; i++) {
                acc[i][j] = __builtin_amdgcn_mfma_f32_16x16x32_f16(ah[i], bh, acc[i][j], 0, 0, 0);
                acc[i][j] = __builtin_amdgcn_mfma_f32_16x16x32_f16(ah[i], bl, acc[i][j], 0, 0, 0);
                acc[i][j] = __builtin_amdgcn_mfma_f32_16x16x32_f16(al[i], bh, acc[i][j], 0, 0, 0);
            }
        }
    }
    const float inv = 1.0f / 512.0f;
    __syncthreads();   // sm dead; reuse as output staging [4 kthL][128][64]
#pragma unroll
    for (int i = 0; i < 4; i++)
#pragma unroll
        for (int j = 0; j < 4; j++) {
            int col = nb * 128 + wc * 64 + j * 16 + r16;
            float bb = b1[col];
            int kthL = (col >> 5) & 3, kk = col & 31;
#pragma unroll
            for (int rr = 0; rr < 4; rr++) {
                int r = wr * 64 + i * 16 + g4 * 4 + rr;
                float v = fmaxf(acc[i][j][rr] * inv + bb, 0.0f) * 8.0f;
                _Float16 h = (_Float16)v;
                _Float16 l = (_Float16)(v - (float)h);
                int off = kthL * 8192 + r * 64 + (kk & 7);
                sm[off + ((((kk >> 3)) ^ (r & 7)) << 3)] = h;
                sm[off + (((4 + (kk >> 3)) ^ (r & 7)) << 3)] = l;
            }
        }
    __syncthreads();
#pragma unroll
    for (int c = 0; c < 16; c++)
        *(half8*)&Xsw[((size_t)(nb * 4 + (c >> 2)) * nMB + mb) * 8192 + (c & 3) * 2048 + t * 8] =
            *(half8*)&sm[c * 2048 + t * 8];
}

// ---------------------------------------------------------------------------
// LSTM GEMM, counted-vmcnt 2-deep pipeline (T3+T4). BM=256, BN=192 (3 gates
// x 64), BK=32, 8 K-steps, 512 threads (8 waves = 4m x 2n), dbuf 2 x 56KB.
// Per iter: vmcnt(7); barrier; 20 ds_read; lgkmcnt(0); barrier; STAGE(k+2);
// setprio(1) 72 MFMA. Loads never drained to 0 mid-loop.
// OUTF32=0: h1 -> H1sw via LDS-staged coalesced store.
// OUTF32=1: fused head partial out10 -> outP.
// ---------------------------------------------------------------------------
template<int OUTF32>
__global__ __launch_bounds__(512, 2) void lstm_kernel(
    const _Float16* __restrict__ Xsw, const _Float16* __restrict__ Wsw,
    const float* __restrict__ bp, float inv,
    _Float16* __restrict__ Hsw,
    const float* __restrict__ W2, float* __restrict__ outP, int nMB, int CB)
{
    extern __shared__ _Float16 lds[];   // 2 x 28672 halves (2 x 56KB)
    const int t = threadIdx.x;
    const int nwg = gridDim.x, hb = blockIdx.x;
    const int per = nwg >> 3;
    const int L = (hb & 7) * per + (hb >> 3);
    const int mb = L >> 2, tile = L & 3;
    const int m0 = mb * 256, n0 = tile * 192;

    auto STAGE = [&](int kt, int buf) {
        _Float16* base = lds + buf * 28672;
        const _Float16* gA = Xsw + ((size_t)kt * nMB + mb) * 16384;
        const _Float16* gB = Wsw + (size_t)(tile * 8 + kt) * 12288;
        int o = t * 8;
#pragma unroll
        for (int it = 0; it < 4; it++)
            gl2lds16(&base[o + it * 4096], &gA[o + it * 4096]);
#pragma unroll
        for (int it = 0; it < 3; it++)
            gl2lds16(&base[16384 + o + it * 4096], &gB[o + it * 4096]);
    };

    const int lane = t & 63, wid = t >> 6;
    const int wr = wid >> 1, wc = wid & 1;
    const int r16 = lane & 15, g4 = lane >> 4;
    const int sx = r16 & 7;
    const int aghi = (g4 ^ sx) << 3;
    const int aglo = ((g4 + 4) ^ sx) << 3;
    f32x4 acc[4][6] = {};

    // Preload biases so the K-loop contains ONLY the STAGE VMEM ops
    // (exact vmcnt counting).
    float pb[6];
#pragma unroll
    for (int u = 0; u < 2; u++) {
        int coll = wc * 32 + u * 16 + r16;
        pb[u * 3 + 0] = bp[n0 + coll];
        pb[u * 3 + 1] = bp[n0 + 64 + coll];
        pb[u * 3 + 2] = bp[n0 + 128 + coll];
    }
    asm volatile("s_waitcnt vmcnt(0)" ::: "memory");
    __builtin_amdgcn_sched_barrier(0);

    STAGE(0, 0);
    STAGE(1, 1);
#pragma unroll
    for (int kt = 0; kt < 8; kt++) {
        if (kt < 7) { asm volatile("s_waitcnt vmcnt(7)" ::: "memory"); }
        else        { asm volatile("s_waitcnt vmcnt(0)" ::: "memory"); }
        __builtin_amdgcn_s_barrier();
        __builtin_amdgcn_sched_barrier(0);
        const _Float16* B = lds + (kt & 1) * 28672;
        half8 ah[4], al[4], bh[6], bl[6];
#pragma unroll
        for (int i = 0; i < 4; i++) {
            int ra = (wr * 64 + i * 16 + r16) * 64;
            ah[i] = *(const half8*)&B[ra + aghi];
            al[i] = *(const half8*)&B[ra + aglo];
        }
#pragma unroll
        for (int j = 0; j < 6; j++) {
            int rb = 16384 + ((j >> 1) * 64 + wc * 32 + (j & 1) * 16 + r16) * 64;
            bh[j] = *(const half8*)&B[rb + aghi];
            bl[j] = *(const half8*)&B[rb + aglo];
        }
        asm volatile("s_waitcnt lgkmcnt(0)" ::: "memory");
        __builtin_amdgcn_sched_barrier(0);
        __builtin_amdgcn_s_barrier();   // all reads of this buffer done
        if (kt < 6) STAGE(kt + 2, kt & 1);
        __builtin_amdgcn_s_setprio(1);
#pragma unroll
        for (int j = 0; j < 6; j++)
#pragma unroll
            for (int i = 0; i < 4; i++) {
                acc[i][j] = __builtin_amdgcn_mfma_f32_16x16x32_f16(ah[i], bh[j], acc[i][j], 0, 0, 0);
                acc[i][j] = __builtin_amdgcn_mfma_f32_16x16x32_f16(ah[i], bl[j], acc[i][j], 0, 0, 0);
                acc[i][j] = __builtin_amdgcn_mfma_f32_16x16x32_f16(al[i], bh[j], acc[i][j], 0, 0, 0);
            }
        __builtin_amdgcn_s_setprio(0);
    }

    if (OUTF32) {
        float* fb  = (float*)lds;              // [256][65] f32
        float* W2s = fb + 256 * 65;            // [10][64]
        __syncthreads();                        // loop buffers dead
#pragma unroll
        for (int i = 0; i < 4; i++)
#pragma unroll
            for (int u = 0; u < 2; u++) {
                int coll = wc * 32 + u * 16 + r16;
#pragma unroll
                for (int rr = 0; rr < 4; rr++) {
                    int rowl = wr * 64 + i * 16 + g4 * 4 + rr;
                    float gi = acc[i][0 + u][rr] * inv + pb[u * 3 + 0];
                    float gg = acc[i][2 + u][rr] * inv + pb[u * 3 + 1];
                    float go = acc[i][4 + u][rr] * inv + pb[u * 3 + 2];
                    float c2 = sigm(gi) * tanh_(gg);
                    fb[rowl * 65 + coll] = sigm(go) * tanh_(c2);
                }
            }
        for (int idx = t; idx < 640; idx += 512)
            W2s[idx] = W2[(idx >> 6) * 256 + tile * 64 + (idx & 63)];
        __syncthreads();
        {
            int r = t & 255, jb = t >> 8;      // 5 outputs: j = jb + 2p
            float s[5] = {0, 0, 0, 0, 0};
            for (int c = 0; c < 64; c++) {
                float hv = fb[r * 65 + c];
#pragma unroll
                for (int p = 0; p < 5; p++) s[p] += hv * W2s[(jb + 2 * p) * 64 + c];
            }
            float* op = outP + ((size_t)tile * CB + m0 + r) * 10;
#pragma unroll
            for (int p = 0; p < 5; p++) op[jb + 2 * p] = s[p];
        }
    } else {
        __syncthreads();                        // loop buffers dead; reuse as [2][256][64]
#pragma unroll
        for (int i = 0; i < 4; i++)
#pragma unroll
            for (int u = 0; u < 2; u++) {
                int coll = wc * 32 + u * 16 + r16;
                int kthL = coll >> 5, kk = coll & 31;
#pragma unroll
                for (int rr = 0; rr < 4; rr++) {
                    int r = wr * 64 + i * 16 + g4 * 4 + rr;
                    float gi = acc[i][0 + u][rr] * inv + pb[u * 3 + 0];
                    float gg = acc[i][2 + u][rr] * inv + pb[u * 3 + 1];
                    float go = acc[i][4 + u][rr] * inv + pb[u * 3 + 2];
                    float c2 = sigm(gi) * tanh_(gg);
                    float v  = 32.0f * sigm(go) * tanh_(c2);
                    _Float16 hh = (_Float16)v;
                    _Float16 ll = (_Float16)(v - (float)hh);
                    int off = kthL * 16384 + r * 64 + (kk & 7);
                    lds[off + ((((kk >> 3)) ^ (r & 7)) << 3)] = hh;
                    lds[off + (((4 + (kk >> 3)) ^ (r & 7)) << 3)] = ll;
                }
            }
        __syncthreads();
#pragma unroll
        for (int c = 0; c < 8; c++)
            *(half8*)&Hsw[((size_t)(2 * tile + (c >> 2)) * nMB + mb) * 16384 + (c & 3) * 4096 + t * 8] =
                *(half8*)&lds[c * 4096 + t * 8];
    }
}

// ---------------------------------------------------------------------------
// Final: sum 4 tile-partials + b2, angles, Y-rotations. One thread per
// (sample, joint).
// ---------------------------------------------------------------------------
__global__ __launch_bounds__(256) void final_kernel(
    const float* __restrict__ outP, const float* __restrict__ b2,
    const float* __restrict__ weight, const int* __restrict__ use_flag,
    const float* __restrict__ aM, const float* __restrict__ wM, const float* __restrict__ RMB,
    float* __restrict__ outA, float* __restrict__ outW, float* __restrict__ outR, int CB)
{
    int tid = blockIdx.x * 256 + threadIdx.x;
    if (tid >= CB * 6) return;
    int i = tid / 6, n = tid - i * 6;
    float c = 1.0f, s = 0.0f;
    if (n < 5) {
        float cr = b2[n], sr = b2[5 + n];
#pragma unroll
        for (int tl = 0; tl < 4; tl++) {
            const float* op = outP + ((size_t)tl * CB + i) * 10;
            cr += op[n]; sr += op[5 + n];
        }
        float delta = (use_flag[0] != 0) ? (1.0f / 90.0f) : (-1.0f / 90.0f);
        float w = fminf(fmaxf(weight[i] + delta, 0.0f), 1.0f);
        float ang = atan2f(sr, cr) * w;
        float sa, ca;
        sincosf(ang, &sa, &ca);
        c = ca; s = -sa;
    }
    {
        const float* ap = aM + (size_t)i * 18 + n * 3;
        float* oa = outA + (size_t)i * 18 + n * 3;
        float a0 = ap[0], a1 = ap[1], a2 = ap[2];
        oa[0] = c * a0 + s * a2; oa[1] = a1; oa[2] = -s * a0 + c * a2;
    }
    {
        const float* wp = wM + (size_t)i * 18 + n * 3;
        float* ow = outW + (size_t)i * 18 + n * 3;
        float a0 = wp[0], a1 = wp[1], a2 = wp[2];
        ow[0] = c * a0 + s * a2; ow[1] = a1; ow[2] = -s * a0 + c * a2;
    }
    const float* rp = RMB + (size_t)i * 54 + n * 9;
    float* orp = outR + (size_t)i * 54 + n * 9;
#pragma unroll
    for (int k = 0; k < 3; k++) {
        float r0 = rp[k], r1 = rp[3 + k], r2 = rp[6 + k];
        orp[k] = c * r0 + s * r2; orp[3 + k] = r1; orp[6 + k] = -s * r0 + c * r2;
    }
}

// ---------------------------------------------------------------------------
extern "C" void kernel_launch(void* const* d_in, const int* in_sizes, int n_in,
                              void* d_out, int out_size, void* d_ws, size_t ws_size,
                              hipStream_t stream)
{
    const float* aM      = (const float*)d_in[0];
    const float* wM      = (const float*)d_in[1];
    const float* RMB     = (const float*)d_in[2];
    const float* weight  = (const float*)d_in[3];
    const float* W1      = (const float*)d_in[4];
    const float* b1      = (const float*)d_in[5];
    const float* Wih0    = (const float*)d_in[6];
    const float* bih0    = (const float*)d_in[8];
    const float* bhh0    = (const float*)d_in[9];
    const float* Wih1    = (const float*)d_in[10];
    const float* bih1    = (const float*)d_in[12];
    const float* bhh1    = (const float*)d_in[13];
    const float* W2      = (const float*)d_in[14];
    const float* b2      = (const float*)d_in[15];
    const int*   use_flag= (const int*)d_in[16];

    char* base = (char*)d_ws;
    size_t off = 0;
    auto alloc = [&](size_t n) { void* p = base + off; off = (off + n + 255) & ~(size_t)255; return p; };

    _Float16* W1sw = (_Float16*)alloc(2 * 16384 * 2);
    _Float16* W0sw = (_Float16*)alloc(4 * 8 * 12288 * 2);
    _Float16* Wssw = (_Float16*)alloc(4 * 8 * 12288 * 2);
    float* bp0 = (float*)alloc(768 * 4);
    float* bp1 = (float*)alloc(768 * 4);
    size_t fixed = off;

    // per-sample: X 1024B + H1 1024B + outP 160B
    size_t perSample = 2208;
    int CB = BTOT;
    while (CB > 2048 && fixed + (size_t)CB * perSample + 65536 > ws_size) CB >>= 1;
    int nMB = CB / 128;      // gemm1 m-blocks
    int nMB2 = CB / 256;     // lstm m-blocks

    _Float16* Xsw  = (_Float16*)alloc((size_t)CB * 1024);   // 512*CB halves
    _Float16* H1sw = (_Float16*)alloc((size_t)CB * 1024);
    float* outP    = (float*)alloc((size_t)CB * 4 * 10 * 4);

    hipFuncSetAttribute((const void*)lstm_kernel<0>,
                        hipFuncAttributeMaxDynamicSharedMemorySize, 114688);
    hipFuncSetAttribute((const void*)lstm_kernel<1>,
                        hipFuncAttributeMaxDynamicSharedMemorySize, 114688);

    pack_kernel<<<1600, 256, 0, stream>>>(W1, Wih0, bih0, bhh0, Wih1, bih1, bhh1,
                                          W1sw, W0sw, bp0, Wssw, bp1);

    float* outA = (float*)d_out;
    float* outW = outA + (size_t)BTOT * 18;
    float* outR = outW + (size_t)BTOT * 18;

    for (int b0 = 0; b0 < BTOT; b0 += CB) {
        gemm1_kernel<<<dim3(CB / 128, 2), 256, 0, stream>>>(
            aM + (size_t)b0 * 18, RMB + (size_t)b0 * 54, W1sw, b1, Xsw, nMB);
        lstm_kernel<0><<<nMB2 * 4, 512, 114688, stream>>>(
            Xsw, W0sw, bp0, 1.0f / 256.0f, H1sw, nullptr, nullptr, nMB2, CB);
        lstm_kernel<1><<<nMB2 * 4, 512, 114688, stream>>>(
            H1sw, Wssw, bp1, 1.0f / 1024.0f, nullptr, W2, outP, nMB2, CB);
        final_kernel<<<CB * 6 / 256, 256, 0, stream>>>(
            outP, b2, weight + b0, use_flag,
            aM + (size_t)b0 * 18, wM + (size_t)b0 * 18, RMB + (size_t)b0 * 54,
            outA + (size_t)b0 * 18, outW + (size_t)b0 * 18, outR + (size_t)b0 * 54, CB);
    }
}

// Round 7
// 200.390 us; speedup vs baseline: 1.0084x; 1.0084x over previous
//
#include <hip/hip_runtime.h>

#define BTOT 32768

using f32x4 = __attribute__((ext_vector_type(4))) float;
using half8 = __attribute__((ext_vector_type(8))) _Float16;

typedef const __attribute__((address_space(1))) unsigned int* gptr_t;
typedef __attribute__((address_space(3))) unsigned int* lptr_t;

__device__ __forceinline__ void gl2lds16(void* lds, const void* g) {
    __builtin_amdgcn_global_load_lds((gptr_t)g, (lptr_t)lds, 16, 0, 0);
}

__device__ __forceinline__ float sigm(float x) {
    return __builtin_amdgcn_rcpf(1.0f + __expf(-x));
}
__device__ __forceinline__ float tanh_(float x) {
    x = fminf(fmaxf(x, -15.0f), 15.0f);
    float e = __expf(2.0f * x);
    return (e - 1.0f) * __builtin_amdgcn_rcpf(e + 1.0f);
}

// ---------------------------------------------------------------------------
// Swizzled layouts: 128B rows of 8 x 16B granules, granule index XOR (row&7).
// LDS image == global image.
//   W1sw: [2 nb][2 kt][128][64]          Wsw: [4 tile][8 kt][192][64]
//   Xsw/H1sw: [8 kt][mb][rows][64]  (mb128 x 128 rows == mb256 x 256 rows)
// ---------------------------------------------------------------------------
__global__ __launch_bounds__(256) void pack_kernel(
    const float* __restrict__ W1,
    const float* __restrict__ Wih0, const float* __restrict__ bih0, const float* __restrict__ bhh0,
    const float* __restrict__ Wih1, const float* __restrict__ bih1, const float* __restrict__ bhh1,
    _Float16* __restrict__ W1sw,
    _Float16* __restrict__ W0sw, float* __restrict__ bp0,
    _Float16* __restrict__ W1sw_, float* __restrict__ bp1)
{
    int tid = blockIdx.x * 256 + threadIdx.x;
    if (tid < 256 * 64) {
        int n = tid >> 6, k = tid & 63;
        float v = (k < 63) ? 32.0f * W1[n * 63 + k] : 0.0f;
        _Float16 h = (_Float16)v;
        _Float16 l = (_Float16)(v - (float)h);
        int nb = n >> 7, r = n & 127, kt = k >> 5, kk = k & 31;
        size_t bb = (size_t)nb * 16384 + kt * 8192 + r * 64 + (kk & 7);
        W1sw[bb + ((((kk >> 3)) ^ (r & 7)) << 3)] = h;
        W1sw[bb + (((4 + (kk >> 3)) ^ (r & 7)) << 3)] = l;
    }
    int t2 = tid - 256 * 64;
    if (t2 >= 0 && t2 < 2 * 768 * 256) {
        int which = t2 / 196608;
        int rem   = t2 % 196608;
        int rlin = rem >> 8, k = rem & 255;
        int tile = rlin / 192;
        int rr = rlin - tile * 192;
        int g = rr >> 6, jj = rr & 63;
        int orig = ((g == 0) ? 0 : (g == 1) ? 512 : 768) + tile * 64 + jj;
        const float* W = which ? Wih1 : Wih0;
        float v = 32.0f * W[orig * 256 + k];
        _Float16 h = (_Float16)v;
        _Float16 l = (_Float16)(v - (float)h);
        int kt = k >> 5, kk = k & 31;
        _Float16* Wd = which ? W1sw_ : W0sw;
        size_t bb = (size_t)(tile * 8 + kt) * 12288 + rr * 64 + (kk & 7);
        Wd[bb + ((((kk >> 3)) ^ (rr & 7)) << 3)] = h;
        Wd[bb + (((4 + (kk >> 3)) ^ (rr & 7)) << 3)] = l;
        if (k == 0) {
            float bb2 = which ? (bih1[orig] + bhh1[orig]) : (bih0[orig] + bhh0[orig]);
            (which ? bp1 : bp0)[rlin] = bb2;
        }
    }
}

// ---------------------------------------------------------------------------
// GEMM1 with fused feature-prep. BM=128, BN=128 (grid.y=2), K=64.
// Output scattered to LDS then stored coalesced (half8).
// ---------------------------------------------------------------------------
__global__ __launch_bounds__(256) void gemm1_kernel(
    const float* __restrict__ aM, const float* __restrict__ RMB,
    const _Float16* __restrict__ W1sw, const float* __restrict__ b1,
    _Float16* __restrict__ Xsw, int nMB)
{
    __shared__ _Float16 sm[32768];   // A:[2kt][128][64]=16384, B same
    const int t = threadIdx.x;
    const int mb = blockIdx.x, nb = blockIdx.y;
    const int m0 = mb * 128;
    {
        int o = t * 8;
#pragma unroll
        for (int it = 0; it < 8; it++)
            gl2lds16(&sm[16384 + o + it * 2048], &W1sw[(size_t)nb * 16384 + o + it * 2048]);
    }
    if (t < 128) {
        int i = m0 + t;
        const float* ap = aM + (size_t)i * 18;
        const float* rp = RMB + (size_t)i * 54;
        float a[18], R[54];
#pragma unroll
        for (int q = 0; q < 9; q++)  { float2 v = *(const float2*)&ap[q * 2]; a[q*2] = v.x; a[q*2+1] = v.y; }
#pragma unroll
        for (int q = 0; q < 27; q++) { float2 v = *(const float2*)&rp[q * 2]; R[q*2] = v.x; R[q*2+1] = v.y; }
        const float* R6 = R + 45;
        float d[64];
        d[0] = -10.0f * R6[3]; d[1] = -10.0f * R6[4]; d[2] = -10.0f * R6[5];
#pragma unroll
        for (int n = 0; n < 5; n++) {
            float v0 = a[n*3+0] - a[15], v1 = a[n*3+1] - a[16], v2 = a[n*3+2] - a[17];
#pragma unroll
            for (int k = 0; k < 3; k++)
                d[3 + n*3 + k] = v0 * R6[k] + v1 * R6[3 + k] + v2 * R6[6 + k];
        }
#pragma unroll
        for (int n = 0; n < 5; n++)
#pragma unroll
            for (int ii = 0; ii < 3; ii++)
#pragma unroll
                for (int k = 0; k < 3; k++)
                    d[18 + n*9 + ii*3 + k] =
                        R6[ii] * R[n*9 + k] + R6[3 + ii] * R[n*9 + 3 + k] + R6[6 + ii] * R[n*9 + 6 + k];
        d[63] = 0.0f;
        int sx = t & 7;
#pragma unroll
        for (int kt = 0; kt < 2; kt++)
#pragma unroll
            for (int kg = 0; kg < 4; kg++) {
                _Float16 hh[8], ll[8];
#pragma unroll
                for (int e = 0; e < 8; e++) {
                    int di = kt * 32 + kg * 8 + e;
                    float v = (di < 63) ? 16.0f * d[di] : 0.0f;
                    _Float16 h = (_Float16)v;
                    hh[e] = h; ll[e] = (_Float16)(v - (float)h);
                }
                int base = kt * 8192 + t * 64;
                *(half8*)&sm[base + ((kg ^ sx) << 3)]       = *(half8*)hh;
                *(half8*)&sm[base + (((kg + 4) ^ sx) << 3)] = *(half8*)ll;
            }
    }
    asm volatile("s_waitcnt vmcnt(0)" ::: "memory");
    __syncthreads();
    const int lane = t & 63, wid = t >> 6;
    const int wr = wid >> 1, wc = wid & 1;
    const int r16 = lane & 15, g4 = lane >> 4;
    const int sx = r16 & 7;
    const int aghi = (g4 ^ sx) << 3;
    const int aglo = ((g4 + 4) ^ sx) << 3;
    f32x4 acc[4][4] = {};
#pragma unroll
    for (int kt = 0; kt < 2; kt++) {
        half8 ah[4], al[4];
#pragma unroll
        for (int i = 0; i < 4; i++) {
            int ra = kt * 8192 + (wr * 64 + i * 16 + r16) * 64;
            ah[i] = *(const half8*)&sm[ra + aghi];
            al[i] = *(const half8*)&sm[ra + aglo];
        }
#pragma unroll
        for (int j = 0; j < 4; j++) {
            int rb = 16384 + kt * 8192 + (wc * 64 + j * 16 + r16) * 64;
            half8 bh = *(const half8*)&sm[rb + aghi];
            half8 bl = *(const half8*)&sm[rb + aglo];
#pragma unroll
            for (int i = 0; i < 4; i++) {
                acc[i][j] = __builtin_amdgcn_mfma_f32_16x16x32_f16(ah[i], bh, acc[i][j], 0, 0, 0);
                acc[i][j] = __builtin_amdgcn_mfma_f32_16x16x32_f16(ah[i], bl, acc[i][j], 0, 0, 0);
                acc[i][j] = __builtin_amdgcn_mfma_f32_16x16x32_f16(al[i], bh, acc[i][j], 0, 0, 0);
            }
        }
    }
    const float inv = 1.0f / 512.0f;
    __syncthreads();   // sm dead; reuse as output staging [4 kthL][128][64]
#pragma unroll
    for (int i = 0; i < 4; i++)
#pragma unroll
        for (int j = 0; j < 4; j++) {
            int col = nb * 128 + wc * 64 + j * 16 + r16;
            float bb = b1[col];
            int kthL = (col >> 5) & 3, kk = col & 31;
#pragma unroll
            for (int rr = 0; rr < 4; rr++) {
                int r = wr * 64 + i * 16 + g4 * 4 + rr;
                float v = fmaxf(acc[i][j][rr] * inv + bb, 0.0f) * 8.0f;
                _Float16 h = (_Float16)v;
                _Float16 l = (_Float16)(v - (float)h);
                int off = kthL * 8192 + r * 64 + (kk & 7);
                sm[off + ((((kk >> 3)) ^ (r & 7)) << 3)] = h;
                sm[off + (((4 + (kk >> 3)) ^ (r & 7)) << 3)] = l;
            }
        }
    __syncthreads();
#pragma unroll
    for (int c = 0; c < 16; c++)
        *(half8*)&Xsw[((size_t)(nb * 4 + (c >> 2)) * nMB + mb) * 8192 + (c & 3) * 2048 + t * 8] =
            *(half8*)&sm[c * 2048 + t * 8];
}

// ---------------------------------------------------------------------------
// LSTM GEMM, single-barrier pipelined loop. BM=256, BN=192, BK=32, 8 K-steps,
// 512 threads (8 waves = 4m x 2n), dbuf 2 x 56KB.
// Per kt: vmcnt(0) [on loads issued a full iter ago = free] -> barrier ->
// issue 20 ds_reads (order pinned) -> STAGE(kt+1 -> other buffer) ->
// lgkmcnt(8) MFMA j01 -> lgkmcnt(4) MFMA j23 -> lgkmcnt(0) MFMA j45.
// ds_reads of j23/j45 fly under the j01 MFMAs; stage flies under everything.
// ---------------------------------------------------------------------------
template<int OUTF32>
__global__ __launch_bounds__(512, 2) void lstm_kernel(
    const _Float16* __restrict__ Xsw, const _Float16* __restrict__ Wsw,
    const float* __restrict__ bp, float inv,
    _Float16* __restrict__ Hsw,
    const float* __restrict__ W2, float* __restrict__ outP, int nMB, int CB)
{
    extern __shared__ _Float16 lds[];   // 2 x 28672 halves (2 x 56KB)
    const int t = threadIdx.x;
    const int nwg = gridDim.x, hb = blockIdx.x;
    const int per = nwg >> 3;
    const int L = (hb & 7) * per + (hb >> 3);
    const int mb = L >> 2, tile = L & 3;
    const int m0 = mb * 256, n0 = tile * 192;

    auto STAGE = [&](int kt, int buf) {
        _Float16* base = lds + buf * 28672;
        const _Float16* gA = Xsw + ((size_t)kt * nMB + mb) * 16384;
        const _Float16* gB = Wsw + (size_t)(tile * 8 + kt) * 12288;
        int o = t * 8;
#pragma unroll
        for (int it = 0; it < 4; it++)
            gl2lds16(&base[o + it * 4096], &gA[o + it * 4096]);
#pragma unroll
        for (int it = 0; it < 3; it++)
            gl2lds16(&base[16384 + o + it * 4096], &gB[o + it * 4096]);
    };

    const int lane = t & 63, wid = t >> 6;
    const int wr = wid >> 1, wc = wid & 1;
    const int r16 = lane & 15, g4 = lane >> 4;
    const int sx = r16 & 7;
    const int aghi = (g4 ^ sx) << 3;
    const int aglo = ((g4 + 4) ^ sx) << 3;
    f32x4 acc[4][6] = {};

    // Preload biases (VMEM, covered by the kt=0 vmcnt(0)).
    float pb[6];
#pragma unroll
    for (int u = 0; u < 2; u++) {
        int coll = wc * 32 + u * 16 + r16;
        pb[u * 3 + 0] = bp[n0 + coll];
        pb[u * 3 + 1] = bp[n0 + 64 + coll];
        pb[u * 3 + 2] = bp[n0 + 128 + coll];
    }

    STAGE(0, 0);
#pragma unroll
    for (int kt = 0; kt < 8; kt++) {
        const int cur = kt & 1;
        // own STAGE(kt) (issued last iteration, except kt=0) + pb landed:
        asm volatile("s_waitcnt vmcnt(0)" ::: "memory");
        __builtin_amdgcn_s_barrier();          // everyone's STAGE landed; all
        __builtin_amdgcn_sched_barrier(0);     // prior reads of other buf done
        const _Float16* Bb = lds + cur * 28672;
        // ---- issue reads, order pinned: [A x8, B01 x4] [B23 x4] [B45 x4]
        half8 ah[4], al[4];
#pragma unroll
        for (int i = 0; i < 4; i++) {
            int ra = (wr * 64 + i * 16 + r16) * 64;
            ah[i] = *(const half8*)&Bb[ra + aghi];
            al[i] = *(const half8*)&Bb[ra + aglo];
        }
        const int rbB = 16384 + (wc * 32 + r16) * 64;
        half8 b0h = *(const half8*)&Bb[rbB + aghi];
        half8 b0l = *(const half8*)&Bb[rbB + aglo];
        half8 b1h = *(const half8*)&Bb[rbB + 1024 + aghi];   // +16 rows
        half8 b1l = *(const half8*)&Bb[rbB + 1024 + aglo];
        __builtin_amdgcn_sched_barrier(0);
        half8 b2h = *(const half8*)&Bb[rbB + 4096 + aghi];   // gate1 = +64 rows
        half8 b2l = *(const half8*)&Bb[rbB + 4096 + aglo];
        half8 b3h = *(const half8*)&Bb[rbB + 5120 + aghi];
        half8 b3l = *(const half8*)&Bb[rbB + 5120 + aglo];
        __builtin_amdgcn_sched_barrier(0);
        half8 b4h = *(const half8*)&Bb[rbB + 8192 + aghi];   // gate2 = +128 rows
        half8 b4l = *(const half8*)&Bb[rbB + 8192 + aglo];
        half8 b5h = *(const half8*)&Bb[rbB + 9216 + aghi];
        half8 b5l = *(const half8*)&Bb[rbB + 9216 + aglo];
        __builtin_amdgcn_sched_barrier(0);
        if (kt < 7) STAGE(kt + 1, cur ^ 1);    // writes the OTHER buffer
        asm volatile("s_waitcnt lgkmcnt(8)" ::: "memory");   // A+B01 done
        __builtin_amdgcn_sched_barrier(0);
        __builtin_amdgcn_s_setprio(1);
#pragma unroll
        for (int i = 0; i < 4; i++) {
            acc[i][0] = __builtin_amdgcn_mfma_f32_16x16x32_f16(ah[i], b0h, acc[i][0], 0, 0, 0);
            acc[i][0] = __builtin_amdgcn_mfma_f32_16x16x32_f16(ah[i], b0l, acc[i][0], 0, 0, 0);
            acc[i][0] = __builtin_amdgcn_mfma_f32_16x16x32_f16(al[i], b0h, acc[i][0], 0, 0, 0);
            acc[i][1] = __builtin_amdgcn_mfma_f32_16x16x32_f16(ah[i], b1h, acc[i][1], 0, 0, 0);
            acc[i][1] = __builtin_amdgcn_mfma_f32_16x16x32_f16(ah[i], b1l, acc[i][1], 0, 0, 0);
            acc[i][1] = __builtin_amdgcn_mfma_f32_16x16x32_f16(al[i], b1h, acc[i][1], 0, 0, 0);
        }
        asm volatile("s_waitcnt lgkmcnt(4)" ::: "memory");   // B23 done
        __builtin_amdgcn_sched_barrier(0);
#pragma unroll
        for (int i = 0; i < 4; i++) {
            acc[i][2] = __builtin_amdgcn_mfma_f32_16x16x32_f16(ah[i], b2h, acc[i][2], 0, 0, 0);
            acc[i][2] = __builtin_amdgcn_mfma_f32_16x16x32_f16(ah[i], b2l, acc[i][2], 0, 0, 0);
            acc[i][2] = __builtin_amdgcn_mfma_f32_16x16x32_f16(al[i], b2h, acc[i][2], 0, 0, 0);
            acc[i][3] = __builtin_amdgcn_mfma_f32_16x16x32_f16(ah[i], b3h, acc[i][3], 0, 0, 0);
            acc[i][3] = __builtin_amdgcn_mfma_f32_16x16x32_f16(ah[i], b3l, acc[i][3], 0, 0, 0);
            acc[i][3] = __builtin_amdgcn_mfma_f32_16x16x32_f16(al[i], b3h, acc[i][3], 0, 0, 0);
        }
        asm volatile("s_waitcnt lgkmcnt(0)" ::: "memory");   // B45 done
        __builtin_amdgcn_sched_barrier(0);
#pragma unroll
        for (int i = 0; i < 4; i++) {
            acc[i][4] = __builtin_amdgcn_mfma_f32_16x16x32_f16(ah[i], b4h, acc[i][4], 0, 0, 0);
            acc[i][4] = __builtin_amdgcn_mfma_f32_16x16x32_f16(ah[i], b4l, acc[i][4], 0, 0, 0);
            acc[i][4] = __builtin_amdgcn_mfma_f32_16x16x32_f16(al[i], b4h, acc[i][4], 0, 0, 0);
            acc[i][5] = __builtin_amdgcn_mfma_f32_16x16x32_f16(ah[i], b5h, acc[i][5], 0, 0, 0);
            acc[i][5] = __builtin_amdgcn_mfma_f32_16x16x32_f16(ah[i], b5l, acc[i][5], 0, 0, 0);
            acc[i][5] = __builtin_amdgcn_mfma_f32_16x16x32_f16(al[i], b5h, acc[i][5], 0, 0, 0);
        }
        __builtin_amdgcn_s_setprio(0);
    }

    if (OUTF32) {
        float* fb  = (float*)lds;              // [256][65] f32
        float* W2s = fb + 256 * 65;            // [10][64]
        __syncthreads();                        // loop buffers dead
#pragma unroll
        for (int i = 0; i < 4; i++)
#pragma unroll
            for (int u = 0; u < 2; u++) {
                int coll = wc * 32 + u * 16 + r16;
#pragma unroll
                for (int rr = 0; rr < 4; rr++) {
                    int rowl = wr * 64 + i * 16 + g4 * 4 + rr;
                    float gi = acc[i][0 + u][rr] * inv + pb[u * 3 + 0];
                    float gg = acc[i][2 + u][rr] * inv + pb[u * 3 + 1];
                    float go = acc[i][4 + u][rr] * inv + pb[u * 3 + 2];
                    float c2 = sigm(gi) * tanh_(gg);
                    fb[rowl * 65 + coll] = sigm(go) * tanh_(c2);
                }
            }
        for (int idx = t; idx < 640; idx += 512)
            W2s[idx] = W2[(idx >> 6) * 256 + tile * 64 + (idx & 63)];
        __syncthreads();
        {
            int r = t & 255, jb = t >> 8;      // 5 outputs: j = jb + 2p
            float s[5] = {0, 0, 0, 0, 0};
            for (int c = 0; c < 64; c++) {
                float hv = fb[r * 65 + c];
#pragma unroll
                for (int p = 0; p < 5; p++) s[p] += hv * W2s[(jb + 2 * p) * 64 + c];
            }
            float* op = outP + (size_t)(m0 + r) * 40 + tile * 10;
#pragma unroll
            for (int p = 0; p < 5; p++) op[jb + 2 * p] = s[p];
        }
    } else {
        __syncthreads();                        // loop buffers dead; reuse as [2][256][64]
#pragma unroll
        for (int i = 0; i < 4; i++)
#pragma unroll
            for (int u = 0; u < 2; u++) {
                int coll = wc * 32 + u * 16 + r16;
                int kthL = coll >> 5, kk = coll & 31;
#pragma unroll
                for (int rr = 0; rr < 4; rr++) {
                    int r = wr * 64 + i * 16 + g4 * 4 + rr;
                    float gi = acc[i][0 + u][rr] * inv + pb[u * 3 + 0];
                    float gg = acc[i][2 + u][rr] * inv + pb[u * 3 + 1];
                    float go = acc[i][4 + u][rr] * inv + pb[u * 3 + 2];
                    float c2 = sigm(gi) * tanh_(gg);
                    float v  = 32.0f * sigm(go) * tanh_(c2);
                    _Float16 hh = (_Float16)v;
                    _Float16 ll = (_Float16)(v - (float)hh);
                    int off = kthL * 16384 + r * 64 + (kk & 7);
                    lds[off + ((((kk >> 3)) ^ (r & 7)) << 3)] = hh;
                    lds[off + (((4 + (kk >> 3)) ^ (r & 7)) << 3)] = ll;
                }
            }
        __syncthreads();
#pragma unroll
        for (int c = 0; c < 8; c++)
            *(half8*)&Hsw[((size_t)(2 * tile + (c >> 2)) * nMB + mb) * 16384 + (c & 3) * 4096 + t * 8] =
                *(half8*)&lds[c * 4096 + t * 8];
    }
}

// ---------------------------------------------------------------------------
// Final: sum 4 tile-partials + b2, angles, Y-rotations. One thread per
// (sample, joint). outP is [CB][4][10] -> contiguous 40 floats per sample.
// ---------------------------------------------------------------------------
__global__ __launch_bounds__(256) void final_kernel(
    const float* __restrict__ outP, const float* __restrict__ b2,
    const float* __restrict__ weight, const int* __restrict__ use_flag,
    const float* __restrict__ aM, const float* __restrict__ wM, const float* __restrict__ RMB,
    float* __restrict__ outA, float* __restrict__ outW, float* __restrict__ outR, int CB)
{
    int tid = blockIdx.x * 256 + threadIdx.x;
    if (tid >= CB * 6) return;
    int i = tid / 6, n = tid - i * 6;
    float c = 1.0f, s = 0.0f;
    if (n < 5) {
        const float* op = outP + (size_t)i * 40;
        float cr = b2[n]     + op[n]     + op[10 + n] + op[20 + n] + op[30 + n];
        float sr = b2[5 + n] + op[5 + n] + op[15 + n] + op[25 + n] + op[35 + n];
        float delta = (use_flag[0] != 0) ? (1.0f / 90.0f) : (-1.0f / 90.0f);
        float w = fminf(fmaxf(weight[i] + delta, 0.0f), 1.0f);
        float ang = atan2f(sr, cr) * w;
        float sa, ca;
        sincosf(ang, &sa, &ca);
        c = ca; s = -sa;
    }
    {
        const float* ap = aM + (size_t)i * 18 + n * 3;
        float* oa = outA + (size_t)i * 18 + n * 3;
        float a0 = ap[0], a1 = ap[1], a2 = ap[2];
        oa[0] = c * a0 + s * a2; oa[1] = a1; oa[2] = -s * a0 + c * a2;
    }
    {
        const float* wp = wM + (size_t)i * 18 + n * 3;
        float* ow = outW + (size_t)i * 18 + n * 3;
        float a0 = wp[0], a1 = wp[1], a2 = wp[2];
        ow[0] = c * a0 + s * a2; ow[1] = a1; ow[2] = -s * a0 + c * a2;
    }
    const float* rp = RMB + (size_t)i * 54 + n * 9;
    float* orp = outR + (size_t)i * 54 + n * 9;
#pragma unroll
    for (int k = 0; k < 3; k++) {
        float r0 = rp[k], r1 = rp[3 + k], r2 = rp[6 + k];
        orp[k] = c * r0 + s * r2; orp[3 + k] = r1; orp[6 + k] = -s * r0 + c * r2;
    }
}

// ---------------------------------------------------------------------------
extern "C" void kernel_launch(void* const* d_in, const int* in_sizes, int n_in,
                              void* d_out, int out_size, void* d_ws, size_t ws_size,
                              hipStream_t stream)
{
    const float* aM      = (const float*)d_in[0];
    const float* wM      = (const float*)d_in[1];
    const float* RMB     = (const float*)d_in[2];
    const float* weight  = (const float*)d_in[3];
    const float* W1      = (const float*)d_in[4];
    const float* b1      = (const float*)d_in[5];
    const float* Wih0    = (const float*)d_in[6];
    const float* bih0    = (const float*)d_in[8];
    const float* bhh0    = (const float*)d_in[9];
    const float* Wih1    = (const float*)d_in[10];
    const float* bih1    = (const float*)d_in[12];
    const float* bhh1    = (const float*)d_in[13];
    const float* W2      = (const float*)d_in[14];
    const float* b2      = (const float*)d_in[15];
    const int*   use_flag= (const int*)d_in[16];

    char* base = (char*)d_ws;
    size_t off = 0;
    auto alloc = [&](size_t n) { void* p = base + off; off = (off + n + 255) & ~(size_t)255; return p; };

    _Float16* W1sw = (_Float16*)alloc(2 * 16384 * 2);
    _Float16* W0sw = (_Float16*)alloc(4 * 8 * 12288 * 2);
    _Float16* Wssw = (_Float16*)alloc(4 * 8 * 12288 * 2);
    float* bp0 = (float*)alloc(768 * 4);
    float* bp1 = (float*)alloc(768 * 4);
    size_t fixed = off;

    // per-sample: X 1024B + H1 1024B + outP 160B
    size_t perSample = 2208;
    int CB = BTOT;
    while (CB > 2048 && fixed + (size_t)CB * perSample + 65536 > ws_size) CB >>= 1;
    int nMB = CB / 128;      // gemm1 m-blocks
    int nMB2 = CB / 256;     // lstm m-blocks

    _Float16* Xsw  = (_Float16*)alloc((size_t)CB * 1024);   // 512*CB halves
    _Float16* H1sw = (_Float16*)alloc((size_t)CB * 1024);
    float* outP    = (float*)alloc((size_t)CB * 40 * 4);

    hipFuncSetAttribute((const void*)lstm_kernel<0>,
                        hipFuncAttributeMaxDynamicSharedMemorySize, 114688);
    hipFuncSetAttribute((const void*)lstm_kernel<1>,
                        hipFuncAttributeMaxDynamicSharedMemorySize, 114688);

    pack_kernel<<<1600, 256, 0, stream>>>(W1, Wih0, bih0, bhh0, Wih1, bih1, bhh1,
                                          W1sw, W0sw, bp0, Wssw, bp1);

    float* outA = (float*)d_out;
    float* outW = outA + (size_t)BTOT * 18;
    float* outR = outW + (size_t)BTOT * 18;

    for (int b0 = 0; b0 < BTOT; b0 += CB) {
        gemm1_kernel<<<dim3(CB / 128, 2), 256, 0, stream>>>(
            aM + (size_t)b0 * 18, RMB + (size_t)b0 * 54, W1sw, b1, Xsw, nMB);
        lstm_kernel<0><<<nMB2 * 4, 512, 114688, stream>>>(
            Xsw, W0sw, bp0, 1.0f / 256.0f, H1sw, nullptr, nullptr, nMB2, CB);
        lstm_kernel<1><<<nMB2 * 4, 512, 114688, stream>>>(
            H1sw, Wssw, bp1, 1.0f / 1024.0f, nullptr, W2, outP, nMB2, CB);
        final_kernel<<<CB * 6 / 256, 256, 0, stream>>>(
            outP, b2, weight + b0, use_flag,
            aM + (size_t)b0 * 18, wM + (size_t)b0 * 18, RMB + (size_t)b0 * 54,
            outA + (size_t)b0 * 18, outW + (size_t)b0 * 18, outR + (size_t)b0 * 54, CB);
    }
}